// Round 2
// baseline (2067.068 us; speedup 1.0000x reference)
//
#include <hip/hip_runtime.h>

// ws float layout:
//  [0:6)   sum1   [6:12)  sumsq1
//  [12:28) sum2   [28:44) sumsq2
//  [44:50) sc1    [50:56) sh1
//  [56:72) sc2    [72:88) sh2
#define WS_SUM1 0
#define WS_SQ1  6
#define WS_SUM2 12
#define WS_SQ2  28
#define WS_SC1  44
#define WS_SH1  50
#define WS_SC2  56
#define WS_SH2  72
#define WS_NFLOATS 88

__device__ __forceinline__ float wave_sum(float v) {
#pragma unroll
  for (int off = 32; off > 0; off >>= 1) v += __shfl_down(v, off, 64);
  return v;
}

__device__ __forceinline__ void load_x(const float* __restrict__ x, size_t t,
                                       float xr[64]) {
  const float4* xp = reinterpret_cast<const float4*>(x + t * 64);
#pragma unroll
  for (int i = 0; i < 16; ++i) {
    float4 v = xp[i];
    xr[4 * i + 0] = v.x; xr[4 * i + 1] = v.y;
    xr[4 * i + 2] = v.z; xr[4 * i + 3] = v.w;
  }
}

// One pooled-front value: meanpool2 of relu(BN1(conv1)) at pooled coords (r,s),
// channel weights wc (uniform global ptr -> s_load), BN fold (sc,sh) uniform.
__device__ __forceinline__ float pooled_val(const float xr[64],
                                            const float* __restrict__ wc,
                                            float bc, float sc, float sh,
                                            int r, int s) {
  float acc = 0.f;
#pragma unroll
  for (int di = 0; di < 2; ++di) {
#pragma unroll
    for (int dj = 0; dj < 2; ++dj) {
      const int ci = 2 * r + di, cj = 2 * s + dj;  // conv1 output coords
      float y = bc;
#pragma unroll
      for (int u = 0; u < 3; ++u) {
        const int xi = ci + u - 2;
        if (xi < 0 || xi > 7) continue;
#pragma unroll
        for (int v = 0; v < 3; ++v) {
          const int xj = cj + v - 2;
          if (xj < 0 || xj > 7) continue;
          y = fmaf(wc[u * 3 + v], xr[xi * 8 + xj], y);
        }
      }
      acc += fmaxf(fmaf(y, sc, sh), 0.f);
    }
  }
  return acc * 0.25f;
}

// ---------------- Kernel A: conv1 raw-output statistics ----------------
__global__ __launch_bounds__(256, 4) void k_stats1(
    const float* __restrict__ x, const float* __restrict__ w1,
    const float* __restrict__ b1, float* __restrict__ ws, int Btot) {
  const int t = blockIdx.x * 256 + threadIdx.x;
  float sum[6], sq[6];
#pragma unroll
  for (int c = 0; c < 6; ++c) { sum[c] = 0.f; sq[c] = 0.f; }

  if (t < Btot) {
    float xr[64];
    load_x(x, (size_t)t, xr);
#pragma unroll
    for (int c = 0; c < 6; ++c) {
      const float* wc = w1 + c * 9;
      const float bc = b1[c];
      float s = 0.f, q = 0.f;
#pragma unroll
      for (int i = 0; i < 10; ++i) {
#pragma unroll
        for (int j = 0; j < 10; ++j) {
          float y = bc;
#pragma unroll
          for (int u = 0; u < 3; ++u) {
            const int xi = i + u - 2;
            if (xi < 0 || xi > 7) continue;
#pragma unroll
            for (int v = 0; v < 3; ++v) {
              const int xj = j + v - 2;
              if (xj < 0 || xj > 7) continue;
              y = fmaf(wc[u * 3 + v], xr[xi * 8 + xj], y);
            }
          }
          s += y;
          q = fmaf(y, y, q);
        }
      }
      sum[c] = s; sq[c] = q;
    }
  }

#pragma unroll
  for (int c = 0; c < 6; ++c) {
    const float s = wave_sum(sum[c]);
    const float q = wave_sum(sq[c]);
    if ((threadIdx.x & 63) == 0) {
      atomicAdd(&ws[WS_SUM1 + c], s);
      atomicAdd(&ws[WS_SQ1 + c], q);
    }
  }
}

// ---------------- fold kernels: BN stats -> (sc, sh) in ws ----------------
__global__ void k_fold1(const float* __restrict__ g1,
                        const float* __restrict__ be1,
                        float* __restrict__ ws, float inv_n) {
  const int c = threadIdx.x;
  if (c < 6) {
    const float mean = ws[WS_SUM1 + c] * inv_n;
    const float var  = ws[WS_SQ1 + c] * inv_n - mean * mean;
    const float sc   = g1[c] * rsqrtf(var + 1e-5f);
    ws[WS_SC1 + c] = sc;
    ws[WS_SH1 + c] = be1[c] - mean * sc;
  }
}

__global__ void k_fold2(const float* __restrict__ g2,
                        const float* __restrict__ be2,
                        float* __restrict__ ws, float inv_n) {
  const int c = threadIdx.x;
  if (c < 16) {
    const float mean = ws[WS_SUM2 + c] * inv_n;
    const float var  = ws[WS_SQ2 + c] * inv_n - mean * mean;
    const float sc   = g2[c] * rsqrtf(var + 1e-5f);
    ws[WS_SC2 + c] = sc;
    ws[WS_SH2 + c] = be2[c] - mean * sc;
  }
}

// ---------------- Kernel B: conv2 output statistics (patch-wise) ----------
// wsf: read-only fold region, wss: atomic sum region (disjoint ranges).
__global__ __launch_bounds__(256, 3) void k_stats2(
    const float* __restrict__ x, const float* __restrict__ w1,
    const float* __restrict__ b1, const float* __restrict__ w2,
    const float* __restrict__ b2, const float* __restrict__ wsf,
    float* __restrict__ wss, int Btot) {
  const int t = blockIdx.x * 256 + threadIdx.x;
  float sum[16], sq[16];
#pragma unroll
  for (int o = 0; o < 16; ++o) { sum[o] = 0.f; sq[o] = 0.f; }

  if (t < Btot) {
    float xr[64];
    load_x(x, (size_t)t, xr);
#pragma unroll
    for (int i2 = 0; i2 < 4; ++i2) {
#pragma unroll
      for (int j2 = 0; j2 < 4; ++j2) {
        float pp[6][2][2];
#pragma unroll
        for (int c = 0; c < 6; ++c) {
          const float* wc = w1 + c * 9;
          const float bc = b1[c];
          const float sc = wsf[WS_SC1 + c];
          const float sh = wsf[WS_SH1 + c];
#pragma unroll
          for (int u = 0; u < 2; ++u)
#pragma unroll
            for (int v = 0; v < 2; ++v)
              pp[c][u][v] = pooled_val(xr, wc, bc, sc, sh, i2 + u, j2 + v);
        }
#pragma unroll
        for (int o = 0; o < 16; ++o) {
          float y = b2[o];
#pragma unroll
          for (int c = 0; c < 6; ++c)
#pragma unroll
            for (int u = 0; u < 2; ++u)
#pragma unroll
              for (int v = 0; v < 2; ++v)
                y = fmaf(w2[o * 24 + c * 4 + u * 2 + v], pp[c][u][v], y);
          sum[o] += y;
          sq[o] = fmaf(y, y, sq[o]);
        }
      }
    }
  }

#pragma unroll
  for (int o = 0; o < 16; ++o) {
    const float s = wave_sum(sum[o]);
    const float q = wave_sum(sq[o]);
    if ((threadIdx.x & 63) == 0) {
      atomicAdd(&wss[WS_SUM2 + o], s);
      atomicAdd(&wss[WS_SQ2 + o], q);
    }
  }
}

// ---------------- Kernel C: full forward (patch-wise) ----------------
__global__ __launch_bounds__(256, 3) void k_final(
    const float* __restrict__ x, const float* __restrict__ w1,
    const float* __restrict__ b1, const float* __restrict__ w2,
    const float* __restrict__ b2, const float* __restrict__ fw1,
    const float* __restrict__ fb1, const float* __restrict__ fw2,
    const float* __restrict__ fb2, const float* __restrict__ fw3,
    const float* __restrict__ fb3, const float* __restrict__ ws,
    float* __restrict__ out, int Btot) {
  const int t = blockIdx.x * 256 + threadIdx.x;
  if (t >= Btot) return;

  float xr[64];
  load_x(x, (size_t)t, xr);

  float h[64];
#pragma unroll
  for (int k = 0; k < 64; ++k) h[k] = 0.f;

#pragma unroll
  for (int i2 = 0; i2 < 4; ++i2) {
#pragma unroll
    for (int j2 = 0; j2 < 4; ++j2) {
      float pp[6][2][2];
#pragma unroll
      for (int c = 0; c < 6; ++c) {
        const float* wc = w1 + c * 9;
        const float bc = b1[c];
        const float sc = ws[WS_SC1 + c];
        const float sh = ws[WS_SH1 + c];
#pragma unroll
        for (int u = 0; u < 2; ++u)
#pragma unroll
          for (int v = 0; v < 2; ++v)
            pp[c][u][v] = pooled_val(xr, wc, bc, sc, sh, i2 + u, j2 + v);
      }
      const int si = i2 >> 1, sj = j2 >> 1;
#pragma unroll
      for (int o = 0; o < 16; ++o) {
        float y = b2[o];
#pragma unroll
        for (int c = 0; c < 6; ++c)
#pragma unroll
          for (int u = 0; u < 2; ++u)
#pragma unroll
            for (int v = 0; v < 2; ++v)
              y = fmaf(w2[o * 24 + c * 4 + u * 2 + v], pp[c][u][v], y);
        const float z = fmaxf(fmaf(y, ws[WS_SC2 + o], ws[WS_SH2 + o]), 0.f);
        h[o * 4 + si * 2 + sj] += 0.25f * z;
      }
    }
  }

  float a1[30];
#pragma unroll
  for (int o = 0; o < 30; ++o) {
    float acc = fb1[o];
#pragma unroll
    for (int j = 0; j < 64; ++j) acc = fmaf(fw1[o * 64 + j], h[j], acc);
    a1[o] = fmaxf(acc, 0.f);
  }

  float a2[15];
#pragma unroll
  for (int o = 0; o < 15; ++o) {
    float acc = fb2[o];
#pragma unroll
    for (int j = 0; j < 30; ++j) acc = fmaf(fw2[o * 30 + j], a1[j], acc);
    a2[o] = fmaxf(acc, 0.f);
  }

  float* op = out + (size_t)t * 10;
#pragma unroll
  for (int o = 0; o < 10; ++o) {
    float acc = fb3[o];
#pragma unroll
    for (int j = 0; j < 15; ++j) acc = fmaf(fw3[o * 15 + j], a2[j], acc);
    op[o] = acc;
  }
}

extern "C" void kernel_launch(void* const* d_in, const int* in_sizes, int n_in,
                              void* d_out, int out_size, void* d_ws, size_t ws_size,
                              hipStream_t stream) {
  (void)n_in; (void)out_size; (void)ws_size;
  const float* x   = (const float*)d_in[0];
  const float* w1  = (const float*)d_in[1];
  const float* b1  = (const float*)d_in[2];
  const float* g1  = (const float*)d_in[3];
  const float* be1 = (const float*)d_in[4];
  const float* w2  = (const float*)d_in[5];
  const float* b2  = (const float*)d_in[6];
  const float* g2  = (const float*)d_in[7];
  const float* be2 = (const float*)d_in[8];
  const float* fw1 = (const float*)d_in[9];
  const float* fb1 = (const float*)d_in[10];
  const float* fw2 = (const float*)d_in[11];
  const float* fb2 = (const float*)d_in[12];
  const float* fw3 = (const float*)d_in[13];
  const float* fb3 = (const float*)d_in[14];
  float* out = (float*)d_out;
  float* ws  = (float*)d_ws;

  const int Btot = in_sizes[0] / 64;
  const float inv_n1 = 1.0f / ((float)Btot * 100.0f);
  const float inv_n2 = 1.0f / ((float)Btot * 16.0f);
  const int grid = (Btot + 255) / 256;

  hipMemsetAsync(ws, 0, WS_NFLOATS * sizeof(float), stream);

  k_stats1<<<grid, 256, 0, stream>>>(x, w1, b1, ws, Btot);
  k_fold1<<<1, 64, 0, stream>>>(g1, be1, ws, inv_n1);
  k_stats2<<<grid, 256, 0, stream>>>(x, w1, b1, w2, b2, ws, ws, Btot);
  k_fold2<<<1, 64, 0, stream>>>(g2, be2, ws, inv_n2);
  k_final<<<grid, 256, 0, stream>>>(x, w1, b1, w2, b2,
                                    fw1, fb1, fw2, fb2, fw3, fb3, ws, out, Btot);
}

// Round 3
// 1099.297 us; speedup vs baseline: 1.8804x; 1.8804x over previous
//
#include <hip/hip_runtime.h>

// ws float layout:
//  [0:6)   sum1   [6:12)  sumsq1
//  [12:28) sum2   [28:44) sumsq2
//  [44:50) sc1    [50:56) sh1
//  [56:72) sc2    [72:88) sh2
#define WS_SUM1 0
#define WS_SQ1  6
#define WS_SUM2 12
#define WS_SQ2  28
#define WS_SC1  44
#define WS_SH1  50
#define WS_SC2  56
#define WS_SH2  72
#define WS_NFLOATS 88

__device__ __forceinline__ float wave_sum(float v) {
#pragma unroll
  for (int off = 32; off > 0; off >>= 1) v += __shfl_down(v, off, 64);
  return v;
}

// ---------------------------------------------------------------------------
// Streaming front: conv1(3x3,pad2) + BN1 + ReLU + meanpool2 + conv2(2x2),
// emitting raw conv2 outputs y(o,i2,j2) (bias included) via `emit`.
// Register footprint: 3-row x window (24) + 2-row pooled buffer (60).
// All weights / BN folds are wave-uniform -> s_load.
// ---------------------------------------------------------------------------
template <class ZFn>
__device__ __forceinline__ void front_conv2(
    const float* __restrict__ x, size_t t,
    const float* __restrict__ w1, const float* __restrict__ b1,
    const float* __restrict__ w2, const float* __restrict__ b2,
    const float* __restrict__ wsf, ZFn&& emit) {
  float xw[3][8];    // rolling window of x rows (row xi lives in xw[xi % 3])
  float prow[6][2][5];  // pooled rows, parity-indexed (holds 4*z sum, scaled later)

#pragma unroll
  for (int ci = 0; ci < 10; ++ci) {  // conv1 output row
    if (ci <= 7) {  // load x row ci
      const float4* xp = reinterpret_cast<const float4*>(x + t * 64 + ci * 8);
      float4 v0 = xp[0], v1 = xp[1];
      xw[ci % 3][0] = v0.x; xw[ci % 3][1] = v0.y;
      xw[ci % 3][2] = v0.z; xw[ci % 3][3] = v0.w;
      xw[ci % 3][4] = v1.x; xw[ci % 3][5] = v1.y;
      xw[ci % 3][6] = v1.z; xw[ci % 3][7] = v1.w;
    }
    const int r = ci >> 1;       // pooled row this conv row feeds
    const int pr = r & 1;        // its parity slot in prow

#pragma unroll
    for (int c = 0; c < 6; ++c) {
      const float bc = b1[c];
      const float sc = wsf[WS_SC1 + c];
      const float sh = wsf[WS_SH1 + c];
#pragma unroll
      for (int j = 0; j < 10; ++j) {
        float y = bc;
#pragma unroll
        for (int u = 0; u < 3; ++u) {
          const int xi = ci + u - 2;
          if (xi < 0 || xi > 7) continue;
#pragma unroll
          for (int v = 0; v < 3; ++v) {
            const int xj = j + v - 2;
            if (xj < 0 || xj > 7) continue;
            y = fmaf(w1[c * 9 + u * 3 + v], xw[xi % 3][xj], y);
          }
        }
        const float z = fmaxf(fmaf(y, sc, sh), 0.f);
        if ((ci & 1) == 0 && (j & 1) == 0) prow[c][pr][j >> 1] = z;
        else                               prow[c][pr][j >> 1] += z;
      }
    }

    // after finishing pooled row r (odd ci), conv2 row i2 = r-1 is ready
    if ((ci & 1) == 1 && r >= 1) {
      const int i2 = r - 1;
#pragma unroll
      for (int o = 0; o < 16; ++o) {
        const float bo = b2[o];
#pragma unroll
        for (int j2 = 0; j2 < 4; ++j2) {
          float acc = 0.f;
#pragma unroll
          for (int c = 0; c < 6; ++c) {
#pragma unroll
            for (int u = 0; u < 2; ++u) {
#pragma unroll
              for (int v = 0; v < 2; ++v) {
                acc = fmaf(w2[o * 24 + c * 4 + u * 2 + v],
                           prow[c][(i2 + u) & 1][j2 + v], acc);
              }
            }
          }
          emit(o, i2, j2, fmaf(acc, 0.25f, bo));  // fold the pool's 1/4 here
        }
      }
    }
  }
}

// ---------------- Kernel A: conv1 raw-output statistics ----------------
__global__ __launch_bounds__(256) void k_stats1(
    const float* __restrict__ x, const float* __restrict__ w1,
    const float* __restrict__ b1, float* __restrict__ ws, int Btot) {
  const int t = blockIdx.x * 256 + threadIdx.x;
  float sum[6], sq[6];
#pragma unroll
  for (int c = 0; c < 6; ++c) { sum[c] = 0.f; sq[c] = 0.f; }

  if (t < Btot) {
    float xw[3][8];
#pragma unroll
    for (int ci = 0; ci < 10; ++ci) {
      if (ci <= 7) {
        const float4* xp = reinterpret_cast<const float4*>(x + (size_t)t * 64 + ci * 8);
        float4 v0 = xp[0], v1 = xp[1];
        xw[ci % 3][0] = v0.x; xw[ci % 3][1] = v0.y;
        xw[ci % 3][2] = v0.z; xw[ci % 3][3] = v0.w;
        xw[ci % 3][4] = v1.x; xw[ci % 3][5] = v1.y;
        xw[ci % 3][6] = v1.z; xw[ci % 3][7] = v1.w;
      }
#pragma unroll
      for (int c = 0; c < 6; ++c) {
        const float bc = b1[c];
#pragma unroll
        for (int j = 0; j < 10; ++j) {
          float y = bc;
#pragma unroll
          for (int u = 0; u < 3; ++u) {
            const int xi = ci + u - 2;
            if (xi < 0 || xi > 7) continue;
#pragma unroll
            for (int v = 0; v < 3; ++v) {
              const int xj = j + v - 2;
              if (xj < 0 || xj > 7) continue;
              y = fmaf(w1[c * 9 + u * 3 + v], xw[xi % 3][xj], y);
            }
          }
          sum[c] += y;
          sq[c] = fmaf(y, y, sq[c]);
        }
      }
    }
  }

#pragma unroll
  for (int c = 0; c < 6; ++c) {
    const float s = wave_sum(sum[c]);
    const float q = wave_sum(sq[c]);
    if ((threadIdx.x & 63) == 0) {
      atomicAdd(&ws[WS_SUM1 + c], s);
      atomicAdd(&ws[WS_SQ1 + c], q);
    }
  }
}

// ---------------- fold kernels: BN stats -> (sc, sh) in ws ----------------
__global__ void k_fold1(const float* __restrict__ g1,
                        const float* __restrict__ be1,
                        float* __restrict__ ws, float inv_n) {
  const int c = threadIdx.x;
  if (c < 6) {
    const float mean = ws[WS_SUM1 + c] * inv_n;
    const float var  = ws[WS_SQ1 + c] * inv_n - mean * mean;
    const float sc   = g1[c] * rsqrtf(var + 1e-5f);
    ws[WS_SC1 + c] = sc;
    ws[WS_SH1 + c] = be1[c] - mean * sc;
  }
}

__global__ void k_fold2(const float* __restrict__ g2,
                        const float* __restrict__ be2,
                        float* __restrict__ ws, float inv_n) {
  const int c = threadIdx.x;
  if (c < 16) {
    const float mean = ws[WS_SUM2 + c] * inv_n;
    const float var  = ws[WS_SQ2 + c] * inv_n - mean * mean;
    const float sc   = g2[c] * rsqrtf(var + 1e-5f);
    ws[WS_SC2 + c] = sc;
    ws[WS_SH2 + c] = be2[c] - mean * sc;
  }
}

// ---------------- Kernel B: conv2 output statistics ----------------
__global__ __launch_bounds__(256) void k_stats2(
    const float* __restrict__ x, const float* __restrict__ w1,
    const float* __restrict__ b1, const float* __restrict__ w2,
    const float* __restrict__ b2, const float* __restrict__ wsf,
    float* __restrict__ wss, int Btot) {
  const int t = blockIdx.x * 256 + threadIdx.x;
  float sum[16], sq[16];
#pragma unroll
  for (int o = 0; o < 16; ++o) { sum[o] = 0.f; sq[o] = 0.f; }

  if (t < Btot) {
    front_conv2(x, (size_t)t, w1, b1, w2, b2, wsf,
                [&](int o, int i2, int j2, float y) {
                  (void)i2; (void)j2;
                  sum[o] += y;
                  sq[o] = fmaf(y, y, sq[o]);
                });
  }

#pragma unroll
  for (int o = 0; o < 16; ++o) {
    const float s = wave_sum(sum[o]);
    const float q = wave_sum(sq[o]);
    if ((threadIdx.x & 63) == 0) {
      atomicAdd(&wss[WS_SUM2 + o], s);
      atomicAdd(&wss[WS_SQ2 + o], q);
    }
  }
}

// ---------------- Kernel C: full forward ----------------
__global__ __launch_bounds__(256) void k_final(
    const float* __restrict__ x, const float* __restrict__ w1,
    const float* __restrict__ b1, const float* __restrict__ w2,
    const float* __restrict__ b2, const float* __restrict__ fw1,
    const float* __restrict__ fb1, const float* __restrict__ fw2,
    const float* __restrict__ fb2, const float* __restrict__ fw3,
    const float* __restrict__ fb3, const float* __restrict__ ws,
    float* __restrict__ out, int Btot) {
  const int t = blockIdx.x * 256 + threadIdx.x;
  if (t >= Btot) return;

  // FC1 fused with BN2+ReLU+meanpool2+flatten:
  // a1[a] = relu(0.25 * sum_z fw1[a][k(z)] * relu(BN2(z)) + fb1[a])
  float a1acc[30];
#pragma unroll
  for (int a = 0; a < 30; ++a) a1acc[a] = 0.f;

  front_conv2(x, (size_t)t, w1, b1, w2, b2, ws,
              [&](int o, int i2, int j2, float y) {
                const float zr =
                    fmaxf(fmaf(y, ws[WS_SC2 + o], ws[WS_SH2 + o]), 0.f);
                const int k = o * 4 + (i2 >> 1) * 2 + (j2 >> 1);
#pragma unroll
                for (int a = 0; a < 30; ++a)
                  a1acc[a] = fmaf(fw1[a * 64 + k], zr, a1acc[a]);
              });

  float a1[30];
#pragma unroll
  for (int a = 0; a < 30; ++a)
    a1[a] = fmaxf(fmaf(0.25f, a1acc[a], fb1[a]), 0.f);

  float a2[15];
#pragma unroll
  for (int o = 0; o < 15; ++o) {
    float acc = fb2[o];
#pragma unroll
    for (int j = 0; j < 30; ++j) acc = fmaf(fw2[o * 30 + j], a1[j], acc);
    a2[o] = fmaxf(acc, 0.f);
  }

  float* op = out + (size_t)t * 10;
#pragma unroll
  for (int o = 0; o < 10; ++o) {
    float acc = fb3[o];
#pragma unroll
    for (int j = 0; j < 15; ++j) acc = fmaf(fw3[o * 15 + j], a2[j], acc);
    op[o] = acc;
  }
}

extern "C" void kernel_launch(void* const* d_in, const int* in_sizes, int n_in,
                              void* d_out, int out_size, void* d_ws, size_t ws_size,
                              hipStream_t stream) {
  (void)n_in; (void)out_size; (void)ws_size;
  const float* x   = (const float*)d_in[0];
  const float* w1  = (const float*)d_in[1];
  const float* b1  = (const float*)d_in[2];
  const float* g1  = (const float*)d_in[3];
  const float* be1 = (const float*)d_in[4];
  const float* w2  = (const float*)d_in[5];
  const float* b2  = (const float*)d_in[6];
  const float* g2  = (const float*)d_in[7];
  const float* be2 = (const float*)d_in[8];
  const float* fw1 = (const float*)d_in[9];
  const float* fb1 = (const float*)d_in[10];
  const float* fw2 = (const float*)d_in[11];
  const float* fb2 = (const float*)d_in[12];
  const float* fw3 = (const float*)d_in[13];
  const float* fb3 = (const float*)d_in[14];
  float* out = (float*)d_out;
  float* ws  = (float*)d_ws;

  const int Btot = in_sizes[0] / 64;
  const float inv_n1 = 1.0f / ((float)Btot * 100.0f);
  const float inv_n2 = 1.0f / ((float)Btot * 16.0f);
  const int grid = (Btot + 255) / 256;

  hipMemsetAsync(ws, 0, WS_NFLOATS * sizeof(float), stream);

  k_stats1<<<grid, 256, 0, stream>>>(x, w1, b1, ws, Btot);
  k_fold1<<<1, 64, 0, stream>>>(g1, be1, ws, inv_n1);
  k_stats2<<<grid, 256, 0, stream>>>(x, w1, b1, w2, b2, ws, ws, Btot);
  k_fold2<<<1, 64, 0, stream>>>(g2, be2, ws, inv_n2);
  k_final<<<grid, 256, 0, stream>>>(x, w1, b1, w2, b2,
                                    fw1, fb1, fw2, fb2, fw3, fb3, ws, out, Btot);
}

// Round 4
// 634.652 us; speedup vs baseline: 3.2570x; 1.7321x over previous
//
#include <hip/hip_runtime.h>

// ws float layout:
//  [0:6)   sum1   [6:12)  sumsq1
//  [12:28) sum2   [28:44) sumsq2
//  [44:50) sc1    [50:56) sh1
//  [56:72) sc2    [72:88) sh2
#define WS_SUM1 0
#define WS_SQ1  6
#define WS_SUM2 12
#define WS_SQ2  28
#define WS_SC1  44
#define WS_SH1  50
#define WS_SC2  56
#define WS_SH2  72
#define WS_NFLOATS 88

#define PST 145  // per-image LDS stride: 12x12 padded image + 1 (bank decorrelation)

__device__ __forceinline__ float wave_sum(float v) {
#pragma unroll
  for (int off = 32; off > 0; off >>= 1) v += __shfl_down(v, off, 64);
  return v;
}

// Stage 16 zero-padded images (12x12, pad=2 border) into LDS.
// Block layout: 256 threads = 16 images x 16 threads. Fully coalesced x read.
// NOTE: requires Btot % 16 == 0 (true here: 131072).
__device__ __forceinline__ void stage_x(const float* __restrict__ x,
                                        float* xl, int blk) {
  const int tid = threadIdx.x;
  for (int i = tid; i < 16 * PST; i += 256) xl[i] = 0.f;
  __syncthreads();
  const float4 v = reinterpret_cast<const float4*>(x)[blk * 256 + tid];
  const int imgl = tid >> 4;
  const int f = (tid & 15) * 4;           // flat elem 0..60 step 4
  const int row = f >> 3, col = f & 7;    // 8x8 coords
  float* dst = xl + imgl * PST + (row + 2) * 12 + (col + 2);
  dst[0] = v.x; dst[1] = v.y; dst[2] = v.z; dst[3] = v.w;
  __syncthreads();
}

// ---------------- Kernel A: conv1 raw-output statistics ----------------
// thread (img, lane16) handles conv1 positions lane16, lane16+16, ... of 100.
__global__ __launch_bounds__(256) void k_stats1(
    const float* __restrict__ x, const float* __restrict__ w1,
    const float* __restrict__ b1, float* ws) {
  __shared__ float xl[16 * PST];
  __shared__ float red[4][12];
  stage_x(x, xl, blockIdx.x);

  const int tid = threadIdx.x;
  const float* base = xl + (tid >> 4) * PST;
  float sum[6], sq[6];
#pragma unroll
  for (int c = 0; c < 6; ++c) { sum[c] = 0.f; sq[c] = 0.f; }

#pragma unroll 1
  for (int p = tid & 15; p < 100; p += 16) {
    const int i = p / 10, j = p % 10;
    const float* pb = base + i * 12 + j;
    float t0 = pb[0],  t1 = pb[1],  t2 = pb[2];
    float t3 = pb[12], t4 = pb[13], t5 = pb[14];
    float t6 = pb[24], t7 = pb[25], t8 = pb[26];
#pragma unroll
    for (int c = 0; c < 6; ++c) {
      float y = b1[c];
      y = fmaf(w1[c * 9 + 0], t0, y); y = fmaf(w1[c * 9 + 1], t1, y);
      y = fmaf(w1[c * 9 + 2], t2, y); y = fmaf(w1[c * 9 + 3], t3, y);
      y = fmaf(w1[c * 9 + 4], t4, y); y = fmaf(w1[c * 9 + 5], t5, y);
      y = fmaf(w1[c * 9 + 6], t6, y); y = fmaf(w1[c * 9 + 7], t7, y);
      y = fmaf(w1[c * 9 + 8], t8, y);
      sum[c] += y;
      sq[c] = fmaf(y, y, sq[c]);
    }
  }

  const int wid = tid >> 6, lane = tid & 63;
#pragma unroll
  for (int c = 0; c < 6; ++c) {
    const float s = wave_sum(sum[c]);
    const float q = wave_sum(sq[c]);
    if (lane == 0) { red[wid][c] = s; red[wid][6 + c] = q; }
  }
  __syncthreads();
  if (tid < 12) {
    const float tot = red[0][tid] + red[1][tid] + red[2][tid] + red[3][tid];
    atomicAdd(&ws[tid < 6 ? WS_SUM1 + tid : WS_SQ1 + tid - 6], tot);
  }
}

// ---------------- fold kernels: BN stats -> (sc, sh) in ws ----------------
__global__ void k_fold1(const float* __restrict__ g1,
                        const float* __restrict__ be1, float* ws, float inv_n) {
  const int c = threadIdx.x;
  if (c < 6) {
    const float mean = ws[WS_SUM1 + c] * inv_n;
    const float var  = ws[WS_SQ1 + c] * inv_n - mean * mean;
    const float sc   = g1[c] * rsqrtf(var + 1e-5f);
    ws[WS_SC1 + c] = sc;
    ws[WS_SH1 + c] = be1[c] - mean * sc;
  }
}

__global__ void k_fold2(const float* __restrict__ g2,
                        const float* __restrict__ be2, float* ws, float inv_n) {
  const int c = threadIdx.x;
  if (c < 16) {
    const float mean = ws[WS_SUM2 + c] * inv_n;
    const float var  = ws[WS_SQ2 + c] * inv_n - mean * mean;
    const float sc   = g2[c] * rsqrtf(var + 1e-5f);
    ws[WS_SC2 + c] = sc;
    ws[WS_SH2 + c] = be2[c] - mean * sc;
  }
}

// Front: from LDS patch -> raw conv2 outputs y[16] at this thread's (i2,j2).
// P = 6x6 x-patch (registers); rolled c-loop keeps code small.
__device__ __forceinline__ void front_y(const float* P,
                                        const float* __restrict__ w1,
                                        const float* __restrict__ b1,
                                        const float* __restrict__ w2,
                                        const float* __restrict__ b2,
                                        const float* wsf, float y[16]) {
#pragma unroll
  for (int o = 0; o < 16; ++o) y[o] = b2[o];
#pragma unroll 1
  for (int c = 0; c < 6; ++c) {
    const float bc = b1[c];
    const float sc = wsf[WS_SC1 + c];
    const float sh = wsf[WS_SH1 + c];
    float zz[16];
#pragma unroll
    for (int ci = 0; ci < 4; ++ci) {
#pragma unroll
      for (int cj = 0; cj < 4; ++cj) {
        float z = bc;
#pragma unroll
        for (int u = 0; u < 3; ++u)
#pragma unroll
          for (int v = 0; v < 3; ++v)
            z = fmaf(w1[c * 9 + u * 3 + v], P[(ci + u) * 6 + cj + v], z);
        zz[ci * 4 + cj] = fmaxf(fmaf(z, sc, sh), 0.f);
      }
    }
    float pp[4];
#pragma unroll
    for (int u = 0; u < 2; ++u)
#pragma unroll
      for (int v = 0; v < 2; ++v)
        pp[u * 2 + v] = 0.25f * (zz[(2 * u) * 4 + 2 * v] + zz[(2 * u) * 4 + 2 * v + 1] +
                                 zz[(2 * u + 1) * 4 + 2 * v] + zz[(2 * u + 1) * 4 + 2 * v + 1]);
#pragma unroll
    for (int o = 0; o < 16; ++o) {
      y[o] = fmaf(w2[o * 24 + c * 4 + 0], pp[0], y[o]);
      y[o] = fmaf(w2[o * 24 + c * 4 + 1], pp[1], y[o]);
      y[o] = fmaf(w2[o * 24 + c * 4 + 2], pp[2], y[o]);
      y[o] = fmaf(w2[o * 24 + c * 4 + 3], pp[3], y[o]);
    }
  }
}

// ---------------- Kernel B: conv2 output statistics ----------------
__global__ __launch_bounds__(256) void k_stats2(
    const float* __restrict__ x, const float* __restrict__ w1,
    const float* __restrict__ b1, const float* __restrict__ w2,
    const float* __restrict__ b2, float* ws) {
  __shared__ float xl[16 * PST];
  __shared__ float red[4][32];
  stage_x(x, xl, blockIdx.x);

  const int tid = threadIdx.x;
  const int pos = tid & 15, i2 = pos >> 2, j2 = pos & 3;
  const float* pb = xl + (tid >> 4) * PST + i2 * 24 + j2 * 2;
  float P[36];
#pragma unroll
  for (int r = 0; r < 6; ++r)
#pragma unroll
    for (int cc = 0; cc < 6; ++cc) P[r * 6 + cc] = pb[r * 12 + cc];

  float y[16];
  front_y(P, w1, b1, w2, b2, ws, y);

  const int wid = tid >> 6, lane = tid & 63;
#pragma unroll
  for (int o = 0; o < 16; ++o) {
    const float s = wave_sum(y[o]);
    const float q = wave_sum(y[o] * y[o]);
    if (lane == 0) { red[wid][o] = s; red[wid][16 + o] = q; }
  }
  __syncthreads();
  if (tid < 32) {
    const float tot = red[0][tid] + red[1][tid] + red[2][tid] + red[3][tid];
    atomicAdd(&ws[tid < 16 ? WS_SUM2 + tid : WS_SQ2 + tid - 16], tot);
  }
}

// ---------------- Kernel C: full forward ----------------
__global__ __launch_bounds__(256) void k_final(
    const float* __restrict__ x, const float* __restrict__ w1,
    const float* __restrict__ b1, const float* __restrict__ w2,
    const float* __restrict__ b2, const float* __restrict__ fw1,
    const float* __restrict__ fb1, const float* __restrict__ fw2,
    const float* __restrict__ fb2, const float* __restrict__ fw3,
    const float* __restrict__ fb3, const float* ws,
    float* __restrict__ out) {
  __shared__ float xl[16 * PST];
  __shared__ float fw1T[64 * 32];   // [k][a], a padded to 32
  __shared__ float lds_h[16 * 68];  // [img][64] stride 68
  __shared__ float lds_a1[16 * 33];
  __shared__ float lds_a2[16 * 17];

  const int tid = threadIdx.x;
  // stage transposed fw1 (zero the a=30,31 pad lanes)
  for (int d = tid; d < 64 * 32; d += 256) {
    const int k = d >> 5, a = d & 31;
    fw1T[d] = (a < 30) ? fw1[a * 64 + k] : 0.f;
  }
  stage_x(x, xl, blockIdx.x);  // includes the needed __syncthreads

  const int imgl = tid >> 4;
  const int pos = tid & 15, i2 = pos >> 2, j2 = pos & 3;
  const float* pb = xl + imgl * PST + i2 * 24 + j2 * 2;
  float P[36];
#pragma unroll
  for (int r = 0; r < 6; ++r)
#pragma unroll
    for (int cc = 0; cc < 6; ++cc) P[r * 6 + cc] = pb[r * 12 + cc];

  float y[16];
  front_y(P, w1, b1, w2, b2, ws, y);

  // BN2 + ReLU + meanpool2 via 4-lane shuffle (j2-pair then i2-pair)
  float hs[16];
#pragma unroll
  for (int o = 0; o < 16; ++o) {
    const float zr = fmaxf(fmaf(y[o], ws[WS_SC2 + o], ws[WS_SH2 + o]), 0.f);
    float tsum = zr + __shfl_xor(zr, 1, 64);
    tsum += __shfl_xor(tsum, 4, 64);
    hs[o] = 0.25f * tsum;
  }
  if ((pos & 5) == 0) {  // pos in {0,2,8,10}: quadrant representatives
    const int si = pos >> 3, sj = (pos & 2) >> 1;
#pragma unroll
    for (int o = 0; o < 16; ++o)
      lds_h[imgl * 68 + o * 4 + si * 2 + sj] = hs[o];
  }
  __syncthreads();

  // FC1: each of 16 lanes computes outputs {al, al+16} for its image
  const int al = pos;
  const float* hrow = lds_h + imgl * 68;
  const bool has2 = (al + 16) < 30;
  float acc0 = fb1[al];
  float acc1 = has2 ? fb1[al + 16] : 0.f;
#pragma unroll 1
  for (int k = 0; k < 64; ++k) {
    const float h = hrow[k];
    acc0 = fmaf(fw1T[k * 32 + al], h, acc0);
    acc1 = fmaf(fw1T[k * 32 + al + 16], h, acc1);
  }
  lds_a1[imgl * 33 + al] = fmaxf(acc0, 0.f);
  if (has2) lds_a1[imgl * 33 + al + 16] = fmaxf(acc1, 0.f);
  __syncthreads();

  // FC2
  if (al < 15) {
    float acc = fb2[al];
#pragma unroll 1
    for (int j = 0; j < 30; ++j)
      acc = fmaf(fw2[al * 30 + j], lds_a1[imgl * 33 + j], acc);
    lds_a2[imgl * 17 + al] = fmaxf(acc, 0.f);
  }
  __syncthreads();

  // FC3 + store
  if (al < 10) {
    float acc = fb3[al];
#pragma unroll 1
    for (int j = 0; j < 15; ++j)
      acc = fmaf(fw3[al * 15 + j], lds_a2[imgl * 17 + j], acc);
    out[(size_t)(blockIdx.x * 16 + imgl) * 10 + al] = acc;
  }
}

extern "C" void kernel_launch(void* const* d_in, const int* in_sizes, int n_in,
                              void* d_out, int out_size, void* d_ws, size_t ws_size,
                              hipStream_t stream) {
  (void)n_in; (void)out_size; (void)ws_size;
  const float* x   = (const float*)d_in[0];
  const float* w1  = (const float*)d_in[1];
  const float* b1  = (const float*)d_in[2];
  const float* g1  = (const float*)d_in[3];
  const float* be1 = (const float*)d_in[4];
  const float* w2  = (const float*)d_in[5];
  const float* b2  = (const float*)d_in[6];
  const float* g2  = (const float*)d_in[7];
  const float* be2 = (const float*)d_in[8];
  const float* fw1 = (const float*)d_in[9];
  const float* fb1 = (const float*)d_in[10];
  const float* fw2 = (const float*)d_in[11];
  const float* fb2 = (const float*)d_in[12];
  const float* fw3 = (const float*)d_in[13];
  const float* fb3 = (const float*)d_in[14];
  float* out = (float*)d_out;
  float* ws  = (float*)d_ws;

  const int Btot = in_sizes[0] / 64;  // 131072; assumed % 16 == 0
  const float inv_n1 = 1.0f / ((float)Btot * 100.0f);
  const float inv_n2 = 1.0f / ((float)Btot * 16.0f);
  const int grid = Btot / 16;

  hipMemsetAsync(ws, 0, WS_NFLOATS * sizeof(float), stream);

  k_stats1<<<grid, 256, 0, stream>>>(x, w1, b1, ws);
  k_fold1<<<1, 64, 0, stream>>>(g1, be1, ws, inv_n1);
  k_stats2<<<grid, 256, 0, stream>>>(x, w1, b1, w2, b2, ws);
  k_fold2<<<1, 64, 0, stream>>>(g2, be2, ws, inv_n2);
  k_final<<<grid, 256, 0, stream>>>(x, w1, b1, w2, b2,
                                    fw1, fb1, fw2, fb2, fw3, fb3, ws, out);
}

// Round 5
// 519.228 us; speedup vs baseline: 3.9810x; 1.2223x over previous
//
#include <hip/hip_runtime.h>

// ws float layout:
//  [0:6)   sum1   [6:12)  sumsq1
//  [12:28) sum2   [28:44) sumsq2
//  [44:50) sc1    [50:56) sh1
//  [56:72) sc2    [72:88) sh2
#define WS_SUM1 0
#define WS_SQ1  6
#define WS_SUM2 12
#define WS_SQ2  28
#define WS_SC1  44
#define WS_SH1  50
#define WS_SC2  56
#define WS_SH2  72
#define WS_NFLOATS 88

#define PST 145  // per-image LDS stride: 12x12 padded image + 1 (bank decorrelation)

__device__ __forceinline__ float wave_sum(float v) {
#pragma unroll
  for (int off = 32; off > 0; off >>= 1) v += __shfl_down(v, off, 64);
  return v;
}

// Stage 16 zero-padded images (12x12, pad=2 border) into LDS.
// Block layout: 256 threads = 16 images x 16 threads. Fully coalesced x read.
// NOTE: requires Btot % 16 == 0 (true here: 131072).
__device__ __forceinline__ void stage_x(const float* __restrict__ x,
                                        float* xl, int blk) {
  const int tid = threadIdx.x;
  for (int i = tid; i < 16 * PST; i += 256) xl[i] = 0.f;
  __syncthreads();
  const float4 v = reinterpret_cast<const float4*>(x)[blk * 256 + tid];
  const int imgl = tid >> 4;
  const int f = (tid & 15) * 4;           // flat elem 0..60 step 4
  const int row = f >> 3, col = f & 7;    // 8x8 coords
  float* dst = xl + imgl * PST + (row + 2) * 12 + (col + 2);
  dst[0] = v.x; dst[1] = v.y; dst[2] = v.z; dst[3] = v.w;
  __syncthreads();
}

// Load this thread's 6x6 padded-x patch into REGISTERS and pin them there
// (the asm keep-alive prevents the compiler from rematerializing the LDS
// loads inside the compute, which was the round-4 bottleneck).
__device__ __forceinline__ void load_patch(const float* pb, float P[36]) {
#pragma unroll
  for (int r = 0; r < 6; ++r)
#pragma unroll
    for (int cc = 0; cc < 6; ++cc) P[r * 6 + cc] = pb[r * 12 + cc];
#pragma unroll
  for (int i = 0; i < 36; ++i) asm volatile("" : "+v"(P[i]));
}

// ---------------- Kernel A: conv1 raw-output statistics ----------------
// thread (img, lane16) handles conv1 positions lane16, lane16+16, ... of 100.
__global__ __launch_bounds__(256) void k_stats1(
    const float* __restrict__ x, const float* __restrict__ w1,
    const float* __restrict__ b1, float* ws) {
  __shared__ float xl[16 * PST];
  __shared__ float red[4][12];
  stage_x(x, xl, blockIdx.x);

  const int tid = threadIdx.x;
  const float* base = xl + (tid >> 4) * PST;
  float sum[6], sq[6];
#pragma unroll
  for (int c = 0; c < 6; ++c) { sum[c] = 0.f; sq[c] = 0.f; }

#pragma unroll 1
  for (int p = tid & 15; p < 100; p += 16) {
    const int i = p / 10, j = p % 10;
    const float* pb = base + i * 12 + j;
    float t0 = pb[0],  t1 = pb[1],  t2 = pb[2];
    float t3 = pb[12], t4 = pb[13], t5 = pb[14];
    float t6 = pb[24], t7 = pb[25], t8 = pb[26];
#pragma unroll
    for (int c = 0; c < 6; ++c) {
      float y = b1[c];
      y = fmaf(w1[c * 9 + 0], t0, y); y = fmaf(w1[c * 9 + 1], t1, y);
      y = fmaf(w1[c * 9 + 2], t2, y); y = fmaf(w1[c * 9 + 3], t3, y);
      y = fmaf(w1[c * 9 + 4], t4, y); y = fmaf(w1[c * 9 + 5], t5, y);
      y = fmaf(w1[c * 9 + 6], t6, y); y = fmaf(w1[c * 9 + 7], t7, y);
      y = fmaf(w1[c * 9 + 8], t8, y);
      sum[c] += y;
      sq[c] = fmaf(y, y, sq[c]);
    }
  }

  const int wid = tid >> 6, lane = tid & 63;
#pragma unroll
  for (int c = 0; c < 6; ++c) {
    const float s = wave_sum(sum[c]);
    const float q = wave_sum(sq[c]);
    if (lane == 0) { red[wid][c] = s; red[wid][6 + c] = q; }
  }
  __syncthreads();
  if (tid < 12) {
    const float tot = red[0][tid] + red[1][tid] + red[2][tid] + red[3][tid];
    atomicAdd(&ws[tid < 6 ? WS_SUM1 + tid : WS_SQ1 + tid - 6], tot);
  }
}

// ---------------- fold kernels: BN stats -> (sc, sh) in ws ----------------
__global__ void k_fold1(const float* __restrict__ g1,
                        const float* __restrict__ be1, float* ws, float inv_n) {
  const int c = threadIdx.x;
  if (c < 6) {
    const float mean = ws[WS_SUM1 + c] * inv_n;
    const float var  = ws[WS_SQ1 + c] * inv_n - mean * mean;
    const float sc   = g1[c] * rsqrtf(var + 1e-5f);
    ws[WS_SC1 + c] = sc;
    ws[WS_SH1 + c] = be1[c] - mean * sc;
  }
}

__global__ void k_fold2(const float* __restrict__ g2,
                        const float* __restrict__ be2, float* ws, float inv_n) {
  const int c = threadIdx.x;
  if (c < 16) {
    const float mean = ws[WS_SUM2 + c] * inv_n;
    const float var  = ws[WS_SQ2 + c] * inv_n - mean * mean;
    const float sc   = g2[c] * rsqrtf(var + 1e-5f);
    ws[WS_SC2 + c] = sc;
    ws[WS_SH2 + c] = be2[c] - mean * sc;
  }
}

// Front: register patch P (pinned) -> raw conv2 outputs y[16] at (i2,j2).
// Fully unrolled: ~1.5K instr, fits I-cache with the 16x decomposition.
__device__ __forceinline__ void front_y(const float P[36],
                                        const float* __restrict__ w1,
                                        const float* __restrict__ b1,
                                        const float* __restrict__ w2,
                                        const float* __restrict__ b2,
                                        const float* wsf, float y[16]) {
#pragma unroll
  for (int o = 0; o < 16; ++o) y[o] = b2[o];
#pragma unroll
  for (int c = 0; c < 6; ++c) {
    const float bc = b1[c];
    const float sc = wsf[WS_SC1 + c];
    const float sh = wsf[WS_SH1 + c];
    float pp[4];
#pragma unroll
    for (int u = 0; u < 2; ++u) {
#pragma unroll
      for (int v = 0; v < 2; ++v) {
        float acc = 0.f;
#pragma unroll
        for (int di = 0; di < 2; ++di) {
#pragma unroll
          for (int dj = 0; dj < 2; ++dj) {
            const int ci = 2 * u + di, cj = 2 * v + dj;
            float z = bc;
#pragma unroll
            for (int uu = 0; uu < 3; ++uu)
#pragma unroll
              for (int vv = 0; vv < 3; ++vv)
                z = fmaf(w1[c * 9 + uu * 3 + vv], P[(ci + uu) * 6 + cj + vv], z);
            acc += fmaxf(fmaf(z, sc, sh), 0.f);
          }
        }
        pp[u * 2 + v] = 0.25f * acc;
      }
    }
#pragma unroll
    for (int o = 0; o < 16; ++o) {
      y[o] = fmaf(w2[o * 24 + c * 4 + 0], pp[0], y[o]);
      y[o] = fmaf(w2[o * 24 + c * 4 + 1], pp[1], y[o]);
      y[o] = fmaf(w2[o * 24 + c * 4 + 2], pp[2], y[o]);
      y[o] = fmaf(w2[o * 24 + c * 4 + 3], pp[3], y[o]);
    }
  }
}

// ---------------- Kernel B: conv2 output statistics ----------------
__global__ __launch_bounds__(256) void k_stats2(
    const float* __restrict__ x, const float* __restrict__ w1,
    const float* __restrict__ b1, const float* __restrict__ w2,
    const float* __restrict__ b2, float* ws) {
  __shared__ float xl[16 * PST];
  __shared__ float red[4][32];
  stage_x(x, xl, blockIdx.x);

  const int tid = threadIdx.x;
  const int pos = tid & 15, i2 = pos >> 2, j2 = pos & 3;
  float P[36];
  load_patch(xl + (tid >> 4) * PST + i2 * 24 + j2 * 2, P);

  float y[16];
  front_y(P, w1, b1, w2, b2, ws, y);

  const int wid = tid >> 6, lane = tid & 63;
#pragma unroll
  for (int o = 0; o < 16; ++o) {
    const float s = wave_sum(y[o]);
    const float q = wave_sum(y[o] * y[o]);
    if (lane == 0) { red[wid][o] = s; red[wid][16 + o] = q; }
  }
  __syncthreads();
  if (tid < 32) {
    const float tot = red[0][tid] + red[1][tid] + red[2][tid] + red[3][tid];
    atomicAdd(&ws[tid < 16 ? WS_SUM2 + tid : WS_SQ2 + tid - 16], tot);
  }
}

// ---------------- Kernel C: full forward ----------------
__global__ __launch_bounds__(256) void k_final(
    const float* __restrict__ x, const float* __restrict__ w1,
    const float* __restrict__ b1, const float* __restrict__ w2,
    const float* __restrict__ b2, const float* __restrict__ fw1,
    const float* __restrict__ fb1, const float* __restrict__ fw2,
    const float* __restrict__ fb2, const float* __restrict__ fw3,
    const float* __restrict__ fb3, const float* ws,
    float* __restrict__ out) {
  __shared__ float xl[16 * PST];
  __shared__ float fw1T[64 * 32];   // [k][a], a padded to 32
  __shared__ float lds_h[16 * 68];  // [img][64] stride 68
  __shared__ float lds_a1[16 * 33];
  __shared__ float lds_a2[16 * 17];

  const int tid = threadIdx.x;
  // stage transposed fw1 (zero the a=30,31 pad lanes)
  for (int d = tid; d < 64 * 32; d += 256) {
    const int k = d >> 5, a = d & 31;
    fw1T[d] = (a < 30) ? fw1[a * 64 + k] : 0.f;
  }
  stage_x(x, xl, blockIdx.x);  // includes the needed __syncthreads

  const int imgl = tid >> 4;
  const int pos = tid & 15, i2 = pos >> 2, j2 = pos & 3;
  float P[36];
  load_patch(xl + imgl * PST + i2 * 24 + j2 * 2, P);

  float y[16];
  front_y(P, w1, b1, w2, b2, ws, y);

  // BN2 + ReLU + meanpool2 via 4-lane shuffle (j2-pair then i2-pair)
  float hs[16];
#pragma unroll
  for (int o = 0; o < 16; ++o) {
    const float zr = fmaxf(fmaf(y[o], ws[WS_SC2 + o], ws[WS_SH2 + o]), 0.f);
    float tsum = zr + __shfl_xor(zr, 1, 64);
    tsum += __shfl_xor(tsum, 4, 64);
    hs[o] = 0.25f * tsum;
  }
  if ((pos & 5) == 0) {  // pos in {0,2,8,10}: quadrant representatives
    const int si = pos >> 3, sj = (pos & 2) >> 1;
#pragma unroll
    for (int o = 0; o < 16; ++o)
      lds_h[imgl * 68 + o * 4 + si * 2 + sj] = hs[o];
  }
  __syncthreads();

  // FC1: each of 16 lanes computes outputs {al, al+16} for its image
  const int al = pos;
  const float* hrow = lds_h + imgl * 68;
  const bool has2 = (al + 16) < 30;
  float acc0 = fb1[al];
  float acc1 = has2 ? fb1[al + 16] : 0.f;
#pragma unroll 8
  for (int k = 0; k < 64; ++k) {
    const float h = hrow[k];
    acc0 = fmaf(fw1T[k * 32 + al], h, acc0);
    acc1 = fmaf(fw1T[k * 32 + al + 16], h, acc1);
  }
  lds_a1[imgl * 33 + al] = fmaxf(acc0, 0.f);
  if (has2) lds_a1[imgl * 33 + al + 16] = fmaxf(acc1, 0.f);
  __syncthreads();

  // FC2
  if (al < 15) {
    float acc = fb2[al];
#pragma unroll 1
    for (int j = 0; j < 30; ++j)
      acc = fmaf(fw2[al * 30 + j], lds_a1[imgl * 33 + j], acc);
    lds_a2[imgl * 17 + al] = fmaxf(acc, 0.f);
  }
  __syncthreads();

  // FC3 + store
  if (al < 10) {
    float acc = fb3[al];
#pragma unroll 1
    for (int j = 0; j < 15; ++j)
      acc = fmaf(fw3[al * 15 + j], lds_a2[imgl * 17 + j], acc);
    out[(size_t)(blockIdx.x * 16 + imgl) * 10 + al] = acc;
  }
}

extern "C" void kernel_launch(void* const* d_in, const int* in_sizes, int n_in,
                              void* d_out, int out_size, void* d_ws, size_t ws_size,
                              hipStream_t stream) {
  (void)n_in; (void)out_size; (void)ws_size;
  const float* x   = (const float*)d_in[0];
  const float* w1  = (const float*)d_in[1];
  const float* b1  = (const float*)d_in[2];
  const float* g1  = (const float*)d_in[3];
  const float* be1 = (const float*)d_in[4];
  const float* w2  = (const float*)d_in[5];
  const float* b2  = (const float*)d_in[6];
  const float* g2  = (const float*)d_in[7];
  const float* be2 = (const float*)d_in[8];
  const float* fw1 = (const float*)d_in[9];
  const float* fb1 = (const float*)d_in[10];
  const float* fw2 = (const float*)d_in[11];
  const float* fb2 = (const float*)d_in[12];
  const float* fw3 = (const float*)d_in[13];
  const float* fb3 = (const float*)d_in[14];
  float* out = (float*)d_out;
  float* ws  = (float*)d_ws;

  const int Btot = in_sizes[0] / 64;  // 131072; assumed % 16 == 0
  const float inv_n1 = 1.0f / ((float)Btot * 100.0f);
  const float inv_n2 = 1.0f / ((float)Btot * 16.0f);
  const int grid = Btot / 16;

  hipMemsetAsync(ws, 0, WS_NFLOATS * sizeof(float), stream);

  k_stats1<<<grid, 256, 0, stream>>>(x, w1, b1, ws);
  k_fold1<<<1, 64, 0, stream>>>(g1, be1, ws, inv_n1);
  k_stats2<<<grid, 256, 0, stream>>>(x, w1, b1, w2, b2, ws);
  k_fold2<<<1, 64, 0, stream>>>(g2, be2, ws, inv_n2);
  k_final<<<grid, 256, 0, stream>>>(x, w1, b1, w2, b2,
                                    fw1, fb1, fw2, fb2, fw3, fb3, ws, out);
}